// Round 10
// baseline (282.014 us; speedup 1.0000x reference)
//
#include <hip/hip_runtime.h>
#include <math.h>

#define BB  8
#define SEQ 2048
#define EMB 512
#define NH  8
#define DH  64
#define NBH (BB * NH)                      // 64
#define MROWS (BB * SEQ)                   // 16384
#define QKV_ELEMS ((size_t)NBH * SEQ * DH) // 8388608
#define MASK_ELEMS (BB * (SEQ - 1))        // 16376
// 512^-0.5 * log2(e): q pre-scaled so softmax uses exp2 directly
#define QSCALE 0.06375871307545f

typedef __attribute__((ext_vector_type(8)))  short short8;
typedef __attribute__((ext_vector_type(4)))  float float4e;
typedef __attribute__((ext_vector_type(16))) float float16e;
typedef __attribute__((ext_vector_type(4)))  unsigned int uint4e;
typedef __attribute__((ext_vector_type(2)))  unsigned int uint2e;
typedef unsigned short ushort_t;

static __device__ inline unsigned short f2bf(float f) {
    unsigned int u = __float_as_uint(f);
    unsigned int r = (u + 0x7fffu + ((u >> 16) & 1u)) >> 16;
    return (unsigned short)r;
}

static __device__ inline void gl_lds16(const unsigned short* g, unsigned short* l) {
    __builtin_amdgcn_global_load_lds(
        (const __attribute__((address_space(1))) void*)g,
        (__attribute__((address_space(3))) void*)l, 16, 0, 0);
}

// ---------------------------------------------------------------------------
// Fused prep: one launch, blockIdx-partitioned.
//   [0, 8192)        conv_x : x fp32 -> xb bf16
//   [8192, 8256)     decode_mask -> pmf f32 [B][SEQ] (1/0, CLS=1) and
//                    pmb u32 [B][SEQ/32] key-valid bitmask (ballot)
//   [8256, 9024)     wtrans Wqkv -> wqt bf16 [1536][512]
//   [9024, 9280)     wtrans Wout -> wot bf16 [512][512]
// ---------------------------------------------------------------------------
#define PREP_CONV   8192
#define PREP_MASK   (PREP_CONV + 64)
#define PREP_WQ     (PREP_MASK + (1536 / 32) * (EMB / 32))
#define PREP_TOTAL  (PREP_WQ + (EMB / 32) * (EMB / 32))

__global__ __launch_bounds__(256) void prep(const float* __restrict__ x,
                                            const void* __restrict__ mraw,
                                            const float* __restrict__ Wqkv,
                                            const float* __restrict__ Wout,
                                            ushort_t* __restrict__ xb,
                                            float* __restrict__ pmf,
                                            unsigned* __restrict__ pmb,
                                            ushort_t* __restrict__ wqt,
                                            ushort_t* __restrict__ wot) {
    __shared__ float T[32][33];
    __shared__ int flag;
    const int bid = blockIdx.x;
    const int tid = threadIdx.x;

    if (bid < PREP_CONV) {
        const size_t i = ((size_t)bid * 256 + tid) * 4;
        float4 v = *(const float4*)&x[i];
        ushort4 o;
        o.x = f2bf(v.x); o.y = f2bf(v.y); o.z = f2bf(v.z); o.w = f2bf(v.w);
        *(ushort4*)&xb[i] = o;
    } else if (bid < PREP_MASK) {
        if (tid == 0) flag = 0;
        __syncthreads();
        const unsigned int* mi = (const unsigned int*)mraw;
        int local = 0;
        for (int i = tid; i < MASK_ELEMS / 4; i += 256) {
            if (mi[i] > 1u) local = 1;
        }
        if (local) flag = 1;
        __syncthreads();
        const int isbyte = flag;
        const unsigned char* mb = (const unsigned char*)mraw;
        const int* m32 = (const int*)mraw;
        const int i = (bid - PREP_CONV) * 256 + tid;
        const int b = i >> 11, n = i & (SEQ - 1);
        int v;
        if (n == 0) v = 1;
        else {
            const int src = b * (SEQ - 1) + n - 1;
            v = isbyte ? (int)mb[src] : (m32[src] != 0 ? 1 : 0);
        }
        pmf[i] = v ? 1.0f : 0.0f;
        // key-valid bitmask: wave = 64 consecutive n (never crosses b)
        const unsigned long long bl = __ballot(v);
        if ((tid & 31) == 0) pmb[i >> 5] = (unsigned)(bl >> (tid & 32));
    } else {
        const float* src;
        ushort_t* dst;
        int N, idx;
        if (bid < PREP_WQ) {
            src = Wqkv; dst = wqt; N = 1536; idx = bid - PREP_MASK;
        } else {
            src = Wout; dst = wot; N = EMB; idx = bid - PREP_WQ;
        }
        const int nb = N / 32;
        const int n0 = (idx % nb) * 32;
        const int k0 = (idx / nb) * 32;
        {
            const int r = tid >> 3, c4 = (tid & 7) * 4;
            *(float4*)&T[r][c4] = *(const float4*)&src[(size_t)(k0 + r) * N + n0 + c4];
        }
        __syncthreads();
        const int n = tid >> 3, k4 = (tid & 7) * 4;
        ushort4 hv;
        hv.x = f2bf(T[k4 + 0][n]);
        hv.y = f2bf(T[k4 + 1][n]);
        hv.z = f2bf(T[k4 + 2][n]);
        hv.w = f2bf(T[k4 + 3][n]);
        *(ushort4*)&dst[(size_t)(n0 + n) * EMB + k0 + k4] = hv;
    }
}

// ---------------------------------------------------------------------------
// MFMA GEMM 1 (v2): qkv = xb @ WqkvT + bqkv. BK=64 + XCD-ownership swizzle.
//   q -> qb [BH][N][DH] (pre-scaled by QSCALE), k -> kb, v -> vt [BH][DH][N].
// ---------------------------------------------------------------------------
__global__ __launch_bounds__(256) void qkv_mfma(const ushort_t* __restrict__ xb,
                                                const ushort_t* __restrict__ wt,
                                                const float* __restrict__ bias,
                                                ushort_t* __restrict__ qb,
                                                ushort_t* __restrict__ kb,
                                                ushort_t* __restrict__ vt) {
    __shared__ __align__(16) ushort_t As[128 * 64];   // 16KB
    __shared__ __align__(16) ushort_t Bs[128 * 64];   // 16KB
    const int tid  = threadIdx.x;
    const int w    = tid >> 6;
    const int lane = tid & 63;
    const int l16  = lane & 15;
    const int quad = lane >> 4;
    const int wq   = w >> 1;
    const int wn   = w & 1;
    const int bid  = blockIdx.x;
    const int c    = bid & 7;
    const int r    = bid >> 3;            // 0..191
    const int mloc = r / 12;
    const int nblk = r - mloc * 12;
    const int row0 = (c * 16 + mloc) * 128;
    const int col0 = nblk * 128;

    float4e acc[4][4];
    #pragma unroll
    for (int i = 0; i < 4; ++i)
        #pragma unroll
        for (int j = 0; j < 4; ++j) acc[i][j] = (float4e){0.f, 0.f, 0.f, 0.f};

    const int srow = tid >> 3;
    const int csrc = (tid & 7) ^ (srow & 7);

    for (int k0 = 0; k0 < EMB; k0 += 64) {
        #pragma unroll
        for (int s = 0; s < 4; ++s) {
            const int row = s * 32 + srow;
            gl_lds16(xb + (size_t)(row0 + row) * EMB + k0 + csrc * 8,
                     As + s * 2048 + w * 512);
            gl_lds16(wt + (size_t)(col0 + row) * EMB + k0 + csrc * 8,
                     Bs + s * 2048 + w * 512);
        }
        __syncthreads();
        #pragma unroll
        for (int kk = 0; kk < 2; ++kk) {
            short8 af[4], bf[4];
            #pragma unroll
            for (int mt = 0; mt < 4; ++mt) {
                const int rm = wq * 64 + mt * 16 + l16;
                af[mt] = *(const short8*)(As + rm * 64 + (((kk * 4 + quad) ^ (rm & 7)) * 8));
            }
            #pragma unroll
            for (int nt = 0; nt < 4; ++nt) {
                const int rn = wn * 64 + nt * 16 + l16;
                bf[nt] = *(const short8*)(Bs + rn * 64 + (((kk * 4 + quad) ^ (rn & 7)) * 8));
            }
            #pragma unroll
            for (int mt = 0; mt < 4; ++mt)
                #pragma unroll
                for (int nt = 0; nt < 4; ++nt)
                    acc[mt][nt] = __builtin_amdgcn_mfma_f32_16x16x32_bf16(af[mt], bf[nt], acc[mt][nt], 0, 0, 0);
        }
        __syncthreads();
    }

    #pragma unroll
    for (int nt = 0; nt < 4; ++nt) {
        const int cb    = col0 + wn * 64 + nt * 16;
        const int which = cb >> 9;
        const int h     = (cb >> 6) & 7;
        const int dcol  = (cb & 63) + l16;
        const float bz  = bias[cb + l16];
        if (which == 2) {
            #pragma unroll
            for (int mt = 0; mt < 4; ++mt) {
                const int rg = row0 + wq * 64 + mt * 16 + quad * 4;
                const int b = rg >> 11, n = rg & (SEQ - 1);
                ushort4 ov;
                ov.x = f2bf(acc[mt][nt][0] + bz);
                ov.y = f2bf(acc[mt][nt][1] + bz);
                ov.z = f2bf(acc[mt][nt][2] + bz);
                ov.w = f2bf(acc[mt][nt][3] + bz);
                *(ushort4*)&vt[((size_t)(b * NH + h) * DH + dcol) * SEQ + n] = ov;
            }
        } else {
            ushort_t* base = (which == 0) ? qb : kb;
            const float sc = (which == 0) ? QSCALE : 1.0f;
            #pragma unroll
            for (int mt = 0; mt < 4; ++mt) {
                #pragma unroll
                for (int i = 0; i < 4; ++i) {
                    const int rg = row0 + wq * 64 + mt * 16 + quad * 4 + i;
                    const int b = rg >> 11;
                    const int n = rg & (SEQ - 1);
                    base[((size_t)(b * NH + h) * SEQ + n) * DH + dcol] =
                        f2bf((acc[mt][nt][i] + bz) * sc);
                }
            }
        }
    }
}

// ---------------------------------------------------------------------------
// MFMA flash attention v16: T15 software-pipelined softmax.
//   R9 barrier-free skeleton, but SM/PV shifted ONE KT BEHIND QK:
//     body(kt): vmcnt(0) [kt landed] -> ds_read vf(kt-1)+kf(kt) -> lgkmcnt+
//     sched_barrier -> stage(kt+1) into vf's vacated buffer -> QK(kt) [MFMA]
//     -> SM(kt-1) [VALU, executes under QK's MFMA shadow] -> PV(kt-1).
//   This removes the per-kt stall where SM waited on QK's dependent MFMA
//   chain (the one axis none of R0-R9's six structures changed).
//   1 chain x 32 q per wave (frees VGPR for the 2-deep st state; R1 proved
//   chains x waves is the invariant). stE/stO rotate via unroll-2 with
//   NAMED registers (rule #20). V-tile swizzle gets a 2nd XOR term
//   (^(vr>>2)&3): 8-way -> 4-way bank conflict.
// ---------------------------------------------------------------------------
__global__ __launch_bounds__(64, 2) void attn_mfma(const ushort_t* __restrict__ qb,
                                                   const ushort_t* __restrict__ kb,
                                                   const ushort_t* __restrict__ vt,
                                                   const float* __restrict__ pmf,
                                                   const unsigned* __restrict__ pmb,
                                                   ushort_t* __restrict__ ab) {
    __shared__ __align__(16) ushort_t Ks0[32 * 64];   // 4KB  K tile buf0
    __shared__ __align__(16) ushort_t Ks1[32 * 64];   // 4KB  K tile buf1
    __shared__ __align__(16) ushort_t Vs0[64 * 32];   // 4KB  V^T tile buf0
    __shared__ __align__(16) ushort_t Vs1[64 * 32];   // 4KB  V^T tile buf1
    __shared__ float lw[32];

    const int lane = threadIdx.x;      // one wave
    const int l5   = lane & 31;
    const int h    = lane >> 5;
    // XCD swizzle: xcd = bid&7 gets bh in [xcd*8, xcd*8+8) -> K+V L2-resident
    const int bid = blockIdx.x;        // 0..4095
    const int ord = bid >> 3;          // 0..511
    const int bh  = (bid & 7) * 8 + (ord >> 6);
    const int qt  = ord & 63;
    const int b   = bh >> 3;
    const int hh  = bh & 7;
    const int q0  = qt * 32;

    // Q fragments (B-operand of S^T): n=q=l5, k=dh=kc*16+h*8+j
    const ushort_t* qbh = qb + (size_t)bh * SEQ * DH;
    short8 qf[4];
    #pragma unroll
    for (int kc = 0; kc < 4; ++kc)
        qf[kc] = *(const short8*)(qbh + (size_t)(q0 + l5) * DH + kc * 16 + h * 8);

    // q mask: masked-q gets zeroed Q and st-init 0 -> p=1 for all keys
    const float mq = pmf[b * SEQ + q0 + l5];
    const bool qv = (mq != 0.0f);
    if (!qv) {
        const short8 z8 = {0, 0, 0, 0, 0, 0, 0, 0};
        #pragma unroll
        for (int kc = 0; kc < 4; ++kc) qf[kc] = z8;
    }

    // key-valid bitmask: lane holds word 'lane' (keys lane*32..+31)
    const unsigned wm = pmb[b * 64 + lane];

    const ushort_t* kbh = kb + (size_t)bh * SEQ * DH;
    const ushort_t* vbh = vt + (size_t)bh * DH * SEQ;

    // staging params (kt-independent). K tile [32 keys][8 slots x 8us];
    // V tile [64 dh][4 slots x 8us], 2-term XOR swizzle.
    const int l3  = lane >> 3;
    const int c8  = (lane & 7) ^ (l3 & 7);
    const int l2  = lane >> 2;
    const int c4v = (lane & 3) ^ ((lane >> 2) & 3) ^ ((lane >> 4) & 3);

    float16e o[2];
    o[0] = (float16e)0.0f;
    o[1] = (float16e)0.0f;
    float l_i = 0.f;

    auto stage = [&](int kt, ushort_t* Kd, ushort_t* Vd) {
        #pragma unroll
        for (int j = 0; j < 4; ++j) {
            gl_lds16(kbh + (size_t)(kt * 32 + j * 8 + l3) * DH + c8 * 8, Kd + j * 512);
            gl_lds16(vbh + (size_t)(j * 16 + l2) * SEQ + kt * 32 + c4v * 8, Vd + j * 512);
        }
    };

    float16e stE, stO;   // st of even / odd kt (named rotation, rule #20)

// body(KT): KC = K buf of KT, KO = other K buf (stage KT+1),
//           VO = V buf of KT-1 (read vf then stage KT+1 over it),
//           STP = st(KT-1) [consumed], STC = st(KT) [produced]
#define ABODY(KT, KC, KO, VO, STP, STC)                                        \
    {                                                                          \
        asm volatile("s_waitcnt vmcnt(0)" ::: "memory");  /* KT landed */      \
        short8 vf[2][2];                                                       \
        _Pragma("unroll")                                                      \
        for (int c = 0; c < 2; ++c)                                            \
            _Pragma("unroll")                                                  \
            for (int d = 0; d < 2; ++d) {                                      \
                const int vr = d * 32 + l5;                                    \
                vf[c][d] = *(const short8*)((VO) + vr * 32 +                   \
                    (((c * 2 + h) ^ (vr & 3) ^ ((vr >> 2) & 3)) * 8));         \
            }                                                                  \
        short8 kf[4];                                                          \
        _Pragma("unroll")                                                      \
        for (int kc = 0; kc < 4; ++kc)                                         \
            kf[kc] = *(const short8*)((KC) + l5 * 64 +                         \
                       (((kc * 2 + h) ^ (l5 & 7)) * 8));                       \
        asm volatile("s_waitcnt lgkmcnt(0)" ::: "memory");                     \
        __builtin_amdgcn_sched_barrier(0);                                     \
        stage((KT) + 1, (KO), (VO));     /* VO vacated: vf in regs */          \
        /* C-init(KT) + QK(KT) -> STC (MFMA, async under SM below) */          \
        {                                                                      \
            const unsigned mwf = (unsigned)__builtin_amdgcn_readlane((int)wm, (KT)); \
            const unsigned mh = h ? (mwf >> 4) : mwf;                          \
            _Pragma("unroll")                                                  \
            for (int j = 0; j < 16; ++j) {                                     \
                const float bv = (mh & (1u << ((j & 3) + 8 * (j >> 2)))) ? 0.0f : -1e9f; \
                (STC)[j] = qv ? bv : 0.0f;                                     \
            }                                                                  \
            __builtin_amdgcn_s_setprio(1);                                     \
            _Pragma("unroll")                                                  \
            for (int kc = 0; kc < 4; ++kc)                                     \
                (STC) = __builtin_amdgcn_mfma_f32_32x32x16_bf16(kf[kc], qf[kc], (STC), 0, 0, 0); \
            __builtin_amdgcn_s_setprio(0);                                     \
        }                                                                      \
        /* SM(KT-1) from STP: pure VALU, no dep on QK(KT) */                   \
        short8 af[2];                                                          \
        {                                                                      \
            unsigned int a[8];                                                 \
            float lacc = 0.f;                                                  \
            _Pragma("unroll")                                                  \
            for (int j = 0; j < 8; ++j) {                                      \
                const float p0 = __builtin_amdgcn_exp2f((STP)[2 * j]);         \
                const float p1 = __builtin_amdgcn_exp2f((STP)[2 * j + 1]);     \
                lacc += p0 + p1;                                               \
                a[j] = (__float_as_uint(p0) >> 16) | (__float_as_uint(p1) & 0xffff0000u); \
            }                                                                  \
            l_i += lacc;                                                       \
            _Pragma("unroll")                                                  \
            for (int c = 0; c < 2; ++c) {                                      \
                const uint2e r02 = __builtin_amdgcn_permlane32_swap(a[4 * c],     a[4 * c + 2], false, false); \
                const uint2e r13 = __builtin_amdgcn_permlane32_swap(a[4 * c + 1], a[4 * c + 3], false, false); \
                uint4e fv;                                                     \
                fv.x = r02[0];                                                 \
                fv.y = r13[0];                                                 \
                fv.z = r02[1];                                                 \
                fv.w = r13[1];                                                 \
                af[c] = __builtin_bit_cast(short8, fv);                        \
            }                                                                  \
        }                                                                      \
        /* PV(KT-1) */                                                         \
        __builtin_amdgcn_s_setprio(1);                                         \
        _Pragma("unroll")                                                      \
        for (int c = 0; c < 2; ++c)                                            \
            _Pragma("unroll")                                                  \
            for (int d = 0; d < 2; ++d)                                        \
                o[d] = __builtin_amdgcn_mfma_f32_32x32x16_bf16(af[c], vf[c][d], o[d], 0, 0, 0); \
        __builtin_amdgcn_s_setprio(0);                                         \
    }

    // ---- prologue: stage(0); wait; stage(1); QK(0) -> stE ----
    stage(0, Ks0, Vs0);
    asm volatile("s_waitcnt vmcnt(0)" ::: "memory");
    stage(1, Ks1, Vs1);
    {
        short8 kf[4];
        #pragma unroll
        for (int kc = 0; kc < 4; ++kc)
            kf[kc] = *(const short8*)(Ks0 + l5 * 64 + (((kc * 2 + h) ^ (l5 & 7)) * 8));
        asm volatile("s_waitcnt lgkmcnt(0)" ::: "memory");
        __builtin_amdgcn_sched_barrier(0);
        const unsigned mwf = (unsigned)__builtin_amdgcn_readlane((int)wm, 0);
        const unsigned mh = h ? (mwf >> 4) : mwf;
        #pragma unroll
        for (int j = 0; j < 16; ++j) {
            const float bv = (mh & (1u << ((j & 3) + 8 * (j >> 2)))) ? 0.0f : -1e9f;
            stE[j] = qv ? bv : 0.0f;
        }
        #pragma unroll
        for (int kc = 0; kc < 4; ++kc)
            stE = __builtin_amdgcn_mfma_f32_32x32x16_bf16(kf[kc], qf[kc], stE, 0, 0, 0);
    }

    // ---- main loop: bodies 1..62 (unroll-2 rotation), then body 63 ----
    for (int kt2 = 1; kt2 < 63; kt2 += 2) {
        ABODY(kt2,     Ks1, Ks0, Vs0, stE, stO)   // odd kt: K in buf1
        ABODY(kt2 + 1, Ks0, Ks1, Vs1, stO, stE)   // even kt: K in buf0
    }
    ABODY(63, Ks1, Ks0, Vs0, stE, stO)            // phantom stage(64): in-bounds of ws, never read

    // ---- epilogue: SM(63) + PV(63); V(63) intact in Vs1 ----
    {
        short8 vf[2][2];
        #pragma unroll
        for (int c = 0; c < 2; ++c)
            #pragma unroll
            for (int d = 0; d < 2; ++d) {
                const int vr = d * 32 + l5;
                vf[c][d] = *(const short8*)(Vs1 + vr * 32 +
                    (((c * 2 + h) ^ (vr & 3) ^ ((vr >> 2) & 3)) * 8));
            }
        unsigned int a[8];
        float lacc = 0.f;
        #pragma unroll
        for (int j = 0; j < 8; ++j) {
            const float p0 = __builtin_amdgcn_exp2f(stO[2 * j]);
            const float p1 = __builtin_amdgcn_exp2f(stO[2 * j + 1]);
            lacc += p0 + p1;
            a[j] = (__float_as_uint(p0) >> 16) | (__float_as_uint(p1) & 0xffff0000u);
        }
        l_i += lacc;
        short8 af[2];
        #pragma unroll
        for (int c = 0; c < 2; ++c) {
            const uint2e r02 = __builtin_amdgcn_permlane32_swap(a[4 * c],     a[4 * c + 2], false, false);
            const uint2e r13 = __builtin_amdgcn_permlane32_swap(a[4 * c + 1], a[4 * c + 3], false, false);
            uint4e fv;
            fv.x = r02[0];
            fv.y = r13[0];
            fv.z = r02[1];
            fv.w = r13[1];
            af[c] = __builtin_bit_cast(short8, fv);
        }
        #pragma unroll
        for (int c = 0; c < 2; ++c)
            #pragma unroll
            for (int d = 0; d < 2; ++d)
                o[d] = __builtin_amdgcn_mfma_f32_32x32x16_bf16(af[c], vf[c][d], o[d], 0, 0, 0);
    }

    // l: combine across half-waves; single wave -> no barrier needed
    {
        const float l = l_i + __shfl_xor(l_i, 32);
        lw[l5] = l;   // both halves write same value
    }

    ushort_t* ob = ab + ((size_t)b * SEQ + q0) * EMB + hh * DH;
    #pragma unroll
    for (int r = 0; r < 16; ++r) {
        const int ql = (r & 3) + 8 * (r >> 2) + 4 * h;
        const float inv = 1.0f / lw[ql];
        #pragma unroll
        for (int d = 0; d < 2; ++d)
            ob[(size_t)ql * EMB + d * 32 + l5] = f2bf(o[d][r] * inv);
    }
#undef ABODY
}

// ---------------------------------------------------------------------------
// MFMA GEMM 2 (v2): out = ab @ WoutT + bout (fp32 out). BK=64 + XCD swizzle.
// ---------------------------------------------------------------------------
__global__ __launch_bounds__(256) void out_mfma(const ushort_t* __restrict__ ab,
                                                const ushort_t* __restrict__ wot,
                                                const float* __restrict__ bias,
                                                float* __restrict__ out) {
    __shared__ __align__(16) ushort_t As[128 * 64];
    __shared__ __align__(16) ushort_t Bs[128 * 64];
    const int tid  = threadIdx.x;
    const int w    = tid >> 6;
    const int lane = tid & 63;
    const int l16  = lane & 15;
    const int quad = lane >> 4;
    const int wq   = w >> 1;
    const int wn   = w & 1;
    const int bid  = blockIdx.x;          // 0..511
    const int c    = bid & 7;
    const int r    = bid >> 3;            // 0..63
    const int mloc = r >> 2;
    const int nblk = r & 3;
    const int row0 = (c * 16 + mloc) * 128;
    const int col0 = nblk * 128;

    float4e acc[4][4];
    #pragma unroll
    for (int i = 0; i < 4; ++i)
        #pragma unroll
        for (int j = 0; j < 4; ++j) acc[i][j] = (float4e){0.f, 0.f, 0.f, 0.f};

    const int srow = tid >> 3;
    const int csrc = (tid & 7) ^ (srow & 7);

    for (int k0 = 0; k0 < EMB; k0 += 64) {
        #pragma unroll
        for (int s = 0; s < 4; ++s) {
            const int row = s * 32 + srow;
            gl_lds16(ab + (size_t)(row0 + row) * EMB + k0 + csrc * 8,
                     As + s * 2048 + w * 512);
            gl_lds16(wot + (size_t)(col0 + row) * EMB + k0 + csrc * 8,
                     Bs + s * 2048 + w * 512);
        }
        __syncthreads();
        #pragma unroll
        for (int kk = 0; kk < 2; ++kk) {
            short8 af[4], bf[4];
            #pragma unroll
            for (int mt = 0; mt < 4; ++mt) {
                const int rm = wq * 64 + mt * 16 + l16;
                af[mt] = *(const short8*)(As + rm * 64 + (((kk * 4 + quad) ^ (rm & 7)) * 8));
            }
            #pragma unroll
            for (int nt = 0; nt < 4; ++nt) {
                const int rn = wn * 64 + nt * 16 + l16;
                bf[nt] = *(const short8*)(Bs + rn * 64 + (((kk * 4 + quad) ^ (rn & 7)) * 8));
            }
            #pragma unroll
            for (int mt = 0; mt < 4; ++mt)
                #pragma unroll
                for (int nt = 0; nt < 4; ++nt)
                    acc[mt][nt] = __builtin_amdgcn_mfma_f32_16x16x32_bf16(af[mt], bf[nt], acc[mt][nt], 0, 0, 0);
        }
        __syncthreads();
    }

    #pragma unroll
    for (int nt = 0; nt < 4; ++nt) {
        const int col_g = col0 + wn * 64 + nt * 16 + l16;
        const float bz = bias[col_g];
        #pragma unroll
        for (int mt = 0; mt < 4; ++mt) {
            #pragma unroll
            for (int i = 0; i < 4; ++i) {
                const int row_g = row0 + wq * 64 + mt * 16 + quad * 4 + i;
                out[(size_t)row_g * EMB + col_g] = acc[mt][nt][i] + bz;
            }
        }
    }
}

// ---------------------------------------------------------------------------
extern "C" void kernel_launch(void* const* d_in, const int* in_sizes, int n_in,
                              void* d_out, int out_size, void* d_ws, size_t ws_size,
                              hipStream_t stream) {
    const float* x    = (const float*)d_in[0];
    const void*  mask = d_in[1];
    const float* Wqkv = (const float*)d_in[2];
    const float* bqkv = (const float*)d_in[3];
    const float* Wout = (const float*)d_in[4];
    const float* bout = (const float*)d_in[5];
    float* out = (float*)d_out;

    ushort_t* xb  = (ushort_t*)d_ws;                 // [16384][512]
    ushort_t* wqt = xb + (size_t)MROWS * EMB;        // [1536][512]
    ushort_t* wot = wqt + (size_t)1536 * EMB;        // [512][512]
    ushort_t* qb  = wot + (size_t)EMB * EMB;         // [BH][N][DH]
    ushort_t* kb  = qb + QKV_ELEMS;
    ushort_t* vt  = kb + QKV_ELEMS;                  // [BH][DH][N]
    ushort_t* ab  = vt + QKV_ELEMS;                  // [B][N][EMB]
    float*    pmf = (float*)(ab + (size_t)MROWS * EMB); // f32 [B][SEQ]
    unsigned* pmb = (unsigned*)(pmf + (size_t)BB * SEQ); // u32 [B][SEQ/32]

    prep<<<dim3(PREP_TOTAL), 256, 0, stream>>>(x, mask, Wqkv, Wout, xb, pmf, pmb, wqt, wot);
    qkv_mfma<<<dim3(1536), 256, 0, stream>>>(xb, wqt, bqkv, qb, kb, vt);
    attn_mfma<<<dim3(NBH * (SEQ / 32)), 64, 0, stream>>>(qb, kb, vt, pmf, pmb, ab);
    out_mfma<<<dim3(512), 256, 0, stream>>>(ab, wot, bout, out);
}

// Round 11
// 242.718 us; speedup vs baseline: 1.1619x; 1.1619x over previous
//
#include <hip/hip_runtime.h>
#include <math.h>

#define BB  8
#define SEQ 2048
#define EMB 512
#define NH  8
#define DH  64
#define NBH (BB * NH)                      // 64
#define MROWS (BB * SEQ)                   // 16384
#define QKV_ELEMS ((size_t)NBH * SEQ * DH) // 8388608
#define MASK_ELEMS (BB * (SEQ - 1))        // 16376
// 512^-0.5 * log2(e): q pre-scaled so softmax uses exp2 directly
#define QSCALE 0.06375871307545f

typedef __attribute__((ext_vector_type(8)))  short short8;
typedef __attribute__((ext_vector_type(4)))  float float4e;
typedef __attribute__((ext_vector_type(16))) float float16e;
typedef __attribute__((ext_vector_type(4)))  unsigned int uint4e;
typedef __attribute__((ext_vector_type(2)))  unsigned int uint2e;
typedef unsigned short ushort_t;

static __device__ inline unsigned short f2bf(float f) {
    unsigned int u = __float_as_uint(f);
    unsigned int r = (u + 0x7fffu + ((u >> 16) & 1u)) >> 16;
    return (unsigned short)r;
}

static __device__ inline void gl_lds16(const unsigned short* g, unsigned short* l) {
    __builtin_amdgcn_global_load_lds(
        (const __attribute__((address_space(1))) void*)g,
        (__attribute__((address_space(3))) void*)l, 16, 0, 0);
}

// ---------------------------------------------------------------------------
// Fused prep: one launch, blockIdx-partitioned.
//   [0, 8192)        conv_x : x fp32 -> xb bf16
//   [8192, 8256)     decode_mask -> pmf f32 [B][SEQ] (1/0, CLS=1),
//                    mkl f32 [B][SEQ] (0 / -1e9), zrow f32 [SEQ] (zeros)
//   [8256, 9024)     wtrans Wqkv -> wqt bf16 [1536][512]
//   [9024, 9280)     wtrans Wout -> wot bf16 [512][512]
// ---------------------------------------------------------------------------
#define PREP_CONV   8192
#define PREP_MASK   (PREP_CONV + 64)
#define PREP_WQ     (PREP_MASK + (1536 / 32) * (EMB / 32))
#define PREP_TOTAL  (PREP_WQ + (EMB / 32) * (EMB / 32))

__global__ __launch_bounds__(256) void prep(const float* __restrict__ x,
                                            const void* __restrict__ mraw,
                                            const float* __restrict__ Wqkv,
                                            const float* __restrict__ Wout,
                                            ushort_t* __restrict__ xb,
                                            float* __restrict__ pmf,
                                            float* __restrict__ mkl,
                                            float* __restrict__ zrow,
                                            ushort_t* __restrict__ wqt,
                                            ushort_t* __restrict__ wot) {
    __shared__ float T[32][33];
    __shared__ int flag;
    const int bid = blockIdx.x;
    const int tid = threadIdx.x;

    if (bid < PREP_CONV) {
        const size_t i = ((size_t)bid * 256 + tid) * 4;
        float4 v = *(const float4*)&x[i];
        ushort4 o;
        o.x = f2bf(v.x); o.y = f2bf(v.y); o.z = f2bf(v.z); o.w = f2bf(v.w);
        *(ushort4*)&xb[i] = o;
    } else if (bid < PREP_MASK) {
        if (tid == 0) flag = 0;
        __syncthreads();
        const unsigned int* mi = (const unsigned int*)mraw;
        int local = 0;
        for (int i = tid; i < MASK_ELEMS / 4; i += 256) {
            if (mi[i] > 1u) local = 1;
        }
        if (local) flag = 1;
        __syncthreads();
        const int isbyte = flag;
        const unsigned char* mb = (const unsigned char*)mraw;
        const int* m32 = (const int*)mraw;
        const int i = (bid - PREP_CONV) * 256 + tid;
        const int b = i >> 11, n = i & (SEQ - 1);
        int v;
        if (n == 0) v = 1;
        else {
            const int src = b * (SEQ - 1) + n - 1;
            v = isbyte ? (int)mb[src] : (m32[src] != 0 ? 1 : 0);
        }
        pmf[i] = v ? 1.0f : 0.0f;
        mkl[i] = v ? 0.0f : -1e9f;
        if (i < SEQ) zrow[i] = 0.0f;
    } else {
        const float* src;
        ushort_t* dst;
        int N, idx;
        if (bid < PREP_WQ) {
            src = Wqkv; dst = wqt; N = 1536; idx = bid - PREP_MASK;
        } else {
            src = Wout; dst = wot; N = EMB; idx = bid - PREP_WQ;
        }
        const int nb = N / 32;
        const int n0 = (idx % nb) * 32;
        const int k0 = (idx / nb) * 32;
        {
            const int r = tid >> 3, c4 = (tid & 7) * 4;
            *(float4*)&T[r][c4] = *(const float4*)&src[(size_t)(k0 + r) * N + n0 + c4];
        }
        __syncthreads();
        const int n = tid >> 3, k4 = (tid & 7) * 4;
        ushort4 hv;
        hv.x = f2bf(T[k4 + 0][n]);
        hv.y = f2bf(T[k4 + 1][n]);
        hv.z = f2bf(T[k4 + 2][n]);
        hv.w = f2bf(T[k4 + 3][n]);
        *(ushort4*)&dst[(size_t)(n0 + n) * EMB + k0 + k4] = hv;
    }
}

// ---------------------------------------------------------------------------
// MFMA GEMM 1 (v3): qkv = xb @ WqkvT + bqkv.
//   BK=32 + DOUBLE-BUFFERED staging (attn's proven pattern): one barrier per
//   K-iter; stage(k0+32)->buf^1 issued right after the barrier so its L2/HBM
//   latency is covered by compute(buf) (16 MFMA + ds_reads). Previous form
//   (stage -> immediate __syncthreads vmcnt(0) drain) exposed full staging
//   latency every iteration. LDS 32KB -> 5 blocks/CU. XCD-ownership grid.
//   q -> qb [BH][N][DH] (pre-scaled by QSCALE), k -> kb, v -> vt [BH][DH][N].
// ---------------------------------------------------------------------------
__global__ __launch_bounds__(256) void qkv_mfma(const ushort_t* __restrict__ xb,
                                                const ushort_t* __restrict__ wt,
                                                const float* __restrict__ bias,
                                                ushort_t* __restrict__ qb,
                                                ushort_t* __restrict__ kb,
                                                ushort_t* __restrict__ vt) {
    __shared__ __align__(16) ushort_t As[2][128 * 32];   // 2 x 8KB
    __shared__ __align__(16) ushort_t Bs[2][128 * 32];   // 2 x 8KB
    const int tid  = threadIdx.x;
    const int w    = tid >> 6;
    const int lane = tid & 63;
    const int l16  = lane & 15;
    const int quad = lane >> 4;
    const int wq   = w >> 1;
    const int wn   = w & 1;
    // XCD-ownership 1D grid (1536 blocks): XCD c owns M-panels [c*16,c*16+16)
    const int bid  = blockIdx.x;
    const int c    = bid & 7;
    const int r    = bid >> 3;            // 0..191
    const int mloc = r / 12;
    const int nblk = r - mloc * 12;
    const int row0 = (c * 16 + mloc) * 128;
    const int col0 = nblk * 128;

    float4e acc[4][4];
    #pragma unroll
    for (int i = 0; i < 4; ++i)
        #pragma unroll
        for (int j = 0; j < 4; ++j) acc[i][j] = (float4e){0.f, 0.f, 0.f, 0.f};

    // staging: 512 chunks of 16B per matrix per buf; 256 thr -> 2 each.
    // LDS chunk c of row r holds source chunk c^(r&3) (XOR swizzle).
    const int srow = tid >> 2;
    const int csrc = (tid & 3) ^ (srow & 3);

    auto stage = [&](int k0, int buf) {
        #pragma unroll
        for (int s = 0; s < 2; ++s) {
            const int row = s * 64 + srow;
            gl_lds16(xb + (size_t)(row0 + row) * EMB + k0 + csrc * 8,
                     As[buf] + s * 2048 + w * 512);
            gl_lds16(wt + (size_t)(col0 + row) * EMB + k0 + csrc * 8,
                     Bs[buf] + s * 2048 + w * 512);
        }
    };

    stage(0, 0);
    for (int k0 = 0; k0 < EMB; k0 += 32) {
        const int cur = (k0 >> 5) & 1;
        __syncthreads();                       // buf[cur] staged & visible
        if (k0 + 32 < EMB) stage(k0 + 32, cur ^ 1);   // overlaps compute

        short8 af[4], bf[4];
        #pragma unroll
        for (int mt = 0; mt < 4; ++mt) {
            const int rm = wq * 64 + mt * 16 + l16;
            af[mt] = *(const short8*)(As[cur] + rm * 32 + ((quad ^ (rm & 3)) * 8));
        }
        #pragma unroll
        for (int nt = 0; nt < 4; ++nt) {
            const int rn = wn * 64 + nt * 16 + l16;
            bf[nt] = *(const short8*)(Bs[cur] + rn * 32 + ((quad ^ (rn & 3)) * 8));
        }
        #pragma unroll
        for (int mt = 0; mt < 4; ++mt)
            #pragma unroll
            for (int nt = 0; nt < 4; ++nt)
                acc[mt][nt] = __builtin_amdgcn_mfma_f32_16x16x32_bf16(af[mt], bf[nt], acc[mt][nt], 0, 0, 0);
    }

    #pragma unroll
    for (int nt = 0; nt < 4; ++nt) {
        const int cb    = col0 + wn * 64 + nt * 16;
        const int which = cb >> 9;
        const int h     = (cb >> 6) & 7;
        const int dcol  = (cb & 63) + l16;
        const float bz  = bias[cb + l16];
        if (which == 2) {
            #pragma unroll
            for (int mt = 0; mt < 4; ++mt) {
                const int rg = row0 + wq * 64 + mt * 16 + quad * 4;
                const int b = rg >> 11, n = rg & (SEQ - 1);
                ushort4 ov;
                ov.x = f2bf(acc[mt][nt][0] + bz);
                ov.y = f2bf(acc[mt][nt][1] + bz);
                ov.z = f2bf(acc[mt][nt][2] + bz);
                ov.w = f2bf(acc[mt][nt][3] + bz);
                *(ushort4*)&vt[((size_t)(b * NH + h) * DH + dcol) * SEQ + n] = ov;
            }
        } else {
            ushort_t* base = (which == 0) ? qb : kb;
            const float sc = (which == 0) ? QSCALE : 1.0f;
            #pragma unroll
            for (int mt = 0; mt < 4; ++mt) {
                #pragma unroll
                for (int i = 0; i < 4; ++i) {
                    const int rg = row0 + wq * 64 + mt * 16 + quad * 4 + i;
                    const int b = rg >> 11;
                    const int n = rg & (SEQ - 1);
                    base[((size_t)(b * NH + h) * SEQ + n) * DH + dcol] =
                        f2bf((acc[mt][nt][i] + bz) * sc);
                }
            }
        }
    }
}

// ---------------------------------------------------------------------------
// MFMA flash attention v10 (R4 verbatim — best measured: 109.5us).
//   K AND V staged in LDS dbuf; 2 waves/block, 64 q per wave (2 chains);
//   C-init mask fold (st starts at mkl 0/-1e9 -> p = exp2(st));
//   permlane32_swap half-wave P exchange; XCD swizzle + setprio.
//   Converged: 7 structural variants (R0/R1/R4/R5/R7/R9/R10) all land
//   109-152us with every pipe <55% — do not touch.
// ---------------------------------------------------------------------------
__device__ inline void stage_tile(const ushort_t* kbh, const ushort_t* vbh, int kt,
                                  ushort_t* Kd, ushort_t* Vd,
                                  const int* crow, const int* csoff, int wbase) {
    #pragma unroll
    for (int j = 0; j < 4; ++j) {
        gl_lds16(kbh + (size_t)(kt * 64 + crow[j]) * DH + csoff[j],
                 Kd + (j * 128 + wbase) * 8);
        gl_lds16(vbh + (size_t)crow[j] * SEQ + kt * 64 + csoff[j],
                 Vd + (j * 128 + wbase) * 8);
    }
}

__global__ __launch_bounds__(128, 2) void attn_mfma(const ushort_t* __restrict__ qb,
                                                    const ushort_t* __restrict__ kb,
                                                    const ushort_t* __restrict__ vt,
                                                    const float* __restrict__ pmf,
                                                    const float* __restrict__ mkl,
                                                    const float* __restrict__ zrow,
                                                    ushort_t* __restrict__ ab) {
    __shared__ __align__(16) ushort_t Ks[2][64 * 64];   // 16KB (dbuf)
    __shared__ __align__(16) ushort_t Vts[2][64 * 64];  // 16KB (dbuf)
    __shared__ float lw[2][64];

    const int tid = threadIdx.x;
    const int w   = tid >> 6;          // 0,1
    const int lane = tid & 63;
    const int l5  = lane & 31;
    const int h   = lane >> 5;         // half-wave
    // XCD swizzle: xcd = bid&7 gets bh in [xcd*8, xcd*8+8) -> 4MB K+V per L2.
    const int bid = blockIdx.x;        // 0..1023
    const int ord = bid >> 3;          // 0..127
    const int bh  = (bid & 7) * 8 + (ord >> 4);
    const int qt  = ord & 15;
    const int b   = bh >> 3;
    const int hh  = bh & 7;
    const int q0  = qt * 128 + w * 64; // wave's first q row

    // Q fragments (B-operand of S^T): n=q=l5, k=dh=kc*16+h*8+j
    const ushort_t* qbh = qb + (size_t)bh * SEQ * DH;
    short8 qf[2][4];
    #pragma unroll
    for (int t = 0; t < 2; ++t)
        #pragma unroll
        for (int kc = 0; kc < 4; ++kc)
            qf[t][kc] = *(const short8*)(qbh + (size_t)(q0 + t * 32 + l5) * DH + kc * 16 + h * 8);

    // q mask: masked-q chains get zeroed Q and read the zeros row as C-init,
    // so st = 0 -> p = 1 for every key (reference's uniform-softmax row).
    const float* crb[2];
    #pragma unroll
    for (int t = 0; t < 2; ++t) {
        const float mq = pmf[b * SEQ + q0 + t * 32 + l5];
        if (mq == 0.0f) {
            const short8 z8 = {0, 0, 0, 0, 0, 0, 0, 0};
            #pragma unroll
            for (int kc = 0; kc < 4; ++kc) qf[t][kc] = z8;
        }
        crb[t] = (mq != 0.0f) ? (mkl + b * SEQ) : zrow;
    }

    // staging chunk params: 512 chunks/tile, 128 thr -> 4 each; swizzle
    // ((c&7)^(row&7)) folded into the SOURCE column.
    int crow[4], csoff[4];
    #pragma unroll
    for (int j = 0; j < 4; ++j) {
        const int c = j * 128 + tid;
        crow[j]  = c >> 3;
        csoff[j] = ((c & 7) ^ (crow[j] & 7)) * 8;
    }
    const int wbase = w * 64;
    const ushort_t* kbh = kb + (size_t)bh * SEQ * DH;
    const ushort_t* vbh = vt + (size_t)bh * DH * SEQ;

    float16e o[2][2];   // [t][dh-tile]
    #pragma unroll
    for (int t = 0; t < 2; ++t)
        #pragma unroll
        for (int d = 0; d < 2; ++d) o[t][d] = (float16e)0.0f;
    float l_i[2] = {0.f, 0.f};

    stage_tile(kbh, vbh, 0, Ks[0], Vts[0], crow, csoff, wbase);

    for (int kt = 0; kt < 32; ++kt) {
        __syncthreads();   // staged tile visible; drain covered by prev compute
        const int cur = kt & 1;
        if (kt < 31)
            stage_tile(kbh, vbh, kt + 1, Ks[cur ^ 1], Vts[cur ^ 1], crow, csoff, wbase);

        #pragma unroll
        for (int s = 0; s < 2; ++s) {
            // ---- C-init: mask logits (0 valid / -1e9 masked), L1-hot ----
            // reg r -> key (r&3)+8*(r>>2)+4h (+s*32)
            float16e st[2];
            #pragma unroll
            for (int t = 0; t < 2; ++t) {
                #pragma unroll
                for (int g2 = 0; g2 < 4; ++g2) {
                    const float4e c4 = *(const float4e*)(crb[t] + kt * 64 + s * 32 + g2 * 8 + h * 4);
                    #pragma unroll
                    for (int j = 0; j < 4; ++j)
                        st[t][g2 * 4 + j] = c4[j];
                }
            }

            // ---- S^T = K·Q per 32-key tile (A=K, B=Q) ----
            const int krow = s * 32 + l5;
            short8 kf[4];
            #pragma unroll
            for (int kc = 0; kc < 4; ++kc)
                kf[kc] = *(const short8*)(Ks[cur] + krow * 64 + (((kc * 2 + h) ^ (krow & 7)) * 8));
            __builtin_amdgcn_s_setprio(1);
            #pragma unroll
            for (int kc = 0; kc < 4; ++kc) {
                st[0] = __builtin_amdgcn_mfma_f32_32x32x16_bf16(kf[kc], qf[0][kc], st[0], 0, 0, 0);
                st[1] = __builtin_amdgcn_mfma_f32_32x32x16_bf16(kf[kc], qf[1][kc], st[1], 0, 0, 0);
            }
            __builtin_amdgcn_s_setprio(0);

            // ---- softmax: p = exp2(st) (mask already in st); pack bf16
            // pairs; half-wave exchange via permlane32_swap -> PV A-frags ----
            short8 af[2][2];
            #pragma unroll
            for (int t = 0; t < 2; ++t) {
                unsigned int a[8];
                float lacc = 0.f;
                #pragma unroll
                for (int j = 0; j < 8; ++j) {
                    const float p0 = __builtin_amdgcn_exp2f(st[t][2 * j]);
                    const float p1 = __builtin_amdgcn_exp2f(st[t][2 * j + 1]);
                    lacc += p0 + p1;
                    a[j] = (__float_as_uint(p0) >> 16) | (__float_as_uint(p1) & 0xffff0000u);
                }
                l_i[t] += lacc;
                #pragma unroll
                for (int c = 0; c < 2; ++c) {
                    const uint2e r02 = __builtin_amdgcn_permlane32_swap(a[4 * c],     a[4 * c + 2], false, false);
                    const uint2e r13 = __builtin_amdgcn_permlane32_swap(a[4 * c + 1], a[4 * c + 3], false, false);
                    uint4e fv;
                    fv.x = r02[0];
                    fv.y = r13[0];
                    fv.z = r02[1];
                    fv.w = r13[1];
                    af[t][c] = __builtin_bit_cast(short8, fv);
                }
            }

            // ---- PV: O[t][d] += P @ V (A=P regs, B=V from LDS) ----
            __builtin_amdgcn_s_setprio(1);
            #pragma unroll
            for (int c = 0; c < 2; ++c) {
                #pragma unroll
                for (int d = 0; d < 2; ++d) {
                    const int vrow = d * 32 + l5;
                    const short8 vf = *(const short8*)(Vts[cur] + vrow * 64 +
                                       (((s * 4 + c * 2 + h) ^ (vrow & 7)) * 8));
                    o[0][d] = __builtin_amdgcn_mfma_f32_32x32x16_bf16(af[0][c], vf, o[0][d], 0, 0, 0);
                    o[1][d] = __builtin_amdgcn_mfma_f32_32x32x16_bf16(af[1][c], vf, o[1][d], 0, 0, 0);
                }
            }
            __builtin_amdgcn_s_setprio(0);
        }
    }

    // l: each half-wave holds its 32-key partials; combine across halves
    #pragma unroll
    for (int t = 0; t < 2; ++t) {
        const float l = l_i[t] + __shfl_xor(l_i[t], 32);
        lw[w][t * 32 + l5] = l;   // both halves write same value
    }

    ushort_t* ob = ab + ((size_t)b * SEQ + q0) * EMB + hh * DH;
    #pragma unroll
    for (int t = 0; t < 2; ++t) {
        #pragma unroll
        for (int r = 0; r < 16; ++r) {
            const int ql = (r & 3) + 8 * (r >> 2) + 4 * h;
            const float inv = 1.0f / lw[w][t * 32 + ql];
            #pragma unroll
            for (int d = 0; d < 2; ++d)
                ob[(size_t)(t * 32 + ql) * EMB + d * 32 + l5] = f2bf(o[t][d][r] * inv);
        }
    }
}

// ---------------------------------------------------------------------------
// MFMA GEMM 2 (v3): out = ab @ WoutT + bout (fp32 out).
//   Same BK=32 double-buffered single-barrier loop as qkv; XCD-ownership
//   grid (512 blocks: XCD c owns M-panels [c*16,c*16+16) x 4 N-blocks).
// ---------------------------------------------------------------------------
__global__ __launch_bounds__(256) void out_mfma(const ushort_t* __restrict__ ab,
                                                const ushort_t* __restrict__ wot,
                                                const float* __restrict__ bias,
                                                float* __restrict__ out) {
    __shared__ __align__(16) ushort_t As[2][128 * 32];
    __shared__ __align__(16) ushort_t Bs[2][128 * 32];
    const int tid  = threadIdx.x;
    const int w    = tid >> 6;
    const int lane = tid & 63;
    const int l16  = lane & 15;
    const int quad = lane >> 4;
    const int wq   = w >> 1;
    const int wn   = w & 1;
    const int bid  = blockIdx.x;          // 0..511
    const int c    = bid & 7;
    const int r    = bid >> 3;            // 0..63
    const int mloc = r >> 2;
    const int nblk = r & 3;
    const int row0 = (c * 16 + mloc) * 128;
    const int col0 = nblk * 128;

    float4e acc[4][4];
    #pragma unroll
    for (int i = 0; i < 4; ++i)
        #pragma unroll
        for (int j = 0; j < 4; ++j) acc[i][j] = (float4e){0.f, 0.f, 0.f, 0.f};

    const int srow = tid >> 2;
    const int csrc = (tid & 3) ^ (srow & 3);

    auto stage = [&](int k0, int buf) {
        #pragma unroll
        for (int s = 0; s < 2; ++s) {
            const int row = s * 64 + srow;
            gl_lds16(ab + (size_t)(row0 + row) * EMB + k0 + csrc * 8,
                     As[buf] + s * 2048 + w * 512);
            gl_lds16(wot + (size_t)(col0 + row) * EMB + k0 + csrc * 8,
                     Bs[buf] + s * 2048 + w * 512);
        }
    };

    stage(0, 0);
    for (int k0 = 0; k0 < EMB; k0 += 32) {
        const int cur = (k0 >> 5) & 1;
        __syncthreads();                       // buf[cur] staged & visible
        if (k0 + 32 < EMB) stage(k0 + 32, cur ^ 1);   // overlaps compute

        short8 af[4], bf[4];
        #pragma unroll
        for (int mt = 0; mt < 4; ++mt) {
            const int rm = wq * 64 + mt * 16 + l16;
            af[mt] = *(const short8*)(As[cur] + rm * 32 + ((quad ^ (rm & 3)) * 8));
        }
        #pragma unroll
        for (int nt = 0; nt < 4; ++nt) {
            const int rn = wn * 64 + nt * 16 + l16;
            bf[nt] = *(const short8*)(Bs[cur] + rn * 32 + ((quad ^ (rn & 3)) * 8));
        }
        #pragma unroll
        for (int mt = 0; mt < 4; ++mt)
            #pragma unroll
            for (int nt = 0; nt < 4; ++nt)
                acc[mt][nt] = __builtin_amdgcn_mfma_f32_16x16x32_bf16(af[mt], bf[nt], acc[mt][nt], 0, 0, 0);
    }

    #pragma unroll
    for (int nt = 0; nt < 4; ++nt) {
        const int col_g = col0 + wn * 64 + nt * 16 + l16;
        const float bz = bias[col_g];
        #pragma unroll
        for (int mt = 0; mt < 4; ++mt) {
            #pragma unroll
            for (int i = 0; i < 4; ++i) {
                const int row_g = row0 + wq * 64 + mt * 16 + quad * 4 + i;
                out[(size_t)row_g * EMB + col_g] = acc[mt][nt][i] + bz;
            }
        }
    }
}

// ---------------------------------------------------------------------------
extern "C" void kernel_launch(void* const* d_in, const int* in_sizes, int n_in,
                              void* d_out, int out_size, void* d_ws, size_t ws_size,
                              hipStream_t stream) {
    const float* x    = (const float*)d_in[0];
    const void*  mask = d_in[1];
    const float* Wqkv = (const float*)d_in[2];
    const float* bqkv = (const float*)d_in[3];
    const float* Wout = (const float*)d_in[4];
    const float* bout = (const float*)d_in[5];
    float* out = (float*)d_out;

    ushort_t* xb  = (ushort_t*)d_ws;                 // [16384][512]
    ushort_t* wqt = xb + (size_t)MROWS * EMB;        // [1536][512]
    ushort_t* wot = wqt + (size_t)1536 * EMB;        // [512][512]
    ushort_t* qb  = wot + (size_t)EMB * EMB;         // [BH][N][DH]
    ushort_t* kb  = qb + QKV_ELEMS;
    ushort_t* vt  = kb + QKV_ELEMS;                  // [BH][DH][N]
    ushort_t* ab  = vt + QKV_ELEMS;                  // [B][N][EMB]
    float*    pmf = (float*)(ab + (size_t)MROWS * EMB); // f32 [B][SEQ]
    float*    mkl = pmf + (size_t)BB * SEQ;             // f32 [B][SEQ]
    float*    zrw = mkl + (size_t)BB * SEQ;             // f32 [SEQ]

    prep<<<dim3(PREP_TOTAL), 256, 0, stream>>>(x, mask, Wqkv, Wout, xb, pmf, mkl, zrw, wqt, wot);
    qkv_mfma<<<dim3(1536), 256, 0, stream>>>(xb, wqt, bqkv, qb, kb, vt);
    attn_mfma<<<dim3(NBH * (SEQ / 128)), 128, 0, stream>>>(qb, kb, vt, pmf, mkl, zrw, ab);
    out_mfma<<<dim3(512), 256, 0, stream>>>(ab, wot, bout, out);
}